// Round 1
// baseline (219.776 us; speedup 1.0000x reference)
//
#include <hip/hip_runtime.h>
#include <hip/hip_bf16.h>

#define NN 8192
#define DD 128

typedef short bf16x8 __attribute__((ext_vector_type(8)));
typedef float f32x4 __attribute__((ext_vector_type(4)));

#define LOG2E 1.4426950408889634f
#define K2f   14.426950408889634f   /* 10 * log2(e) */

// ws layout: [0, 2 MB) bf16 features; then N floats m_i; then one int class-count
#define M_OFF   (NN * DD * 2)
#define CNT_OFF (M_OFF + NN * 4)

__device__ __forceinline__ unsigned short f2bf(float x) {
    unsigned u = __float_as_uint(x);
    u = (u + 0x7FFFu + ((u >> 16) & 1u)) >> 16;   // RNE to bf16
    return (unsigned short)u;
}

// One wave per row: convert fp32 -> bf16, compute m_i = 10*||f||^2, count label-1s.
__global__ __launch_bounds__(64) void prep_kernel(const float* __restrict__ F,
        const int* __restrict__ labels, unsigned short* __restrict__ F16,
        float* __restrict__ M, int* __restrict__ cnt1) {
    const int row  = blockIdx.x;
    const int lane = threadIdx.x;
    const float2 f = *reinterpret_cast<const float2*>(F + row * DD + lane * 2);
    ushort2 u; u.x = f2bf(f.x); u.y = f2bf(f.y);
    *reinterpret_cast<ushort2*>(F16 + row * DD + lane * 2) = u;
    float ss = fmaf(f.x, f.x, f.y * f.y);
    #pragma unroll
    for (int off = 1; off < 64; off <<= 1) ss += __shfl_xor(ss, off);
    if (lane == 0) {
        M[row] = 10.0f * ss;
        atomicAdd(cnt1, labels[row]);
    }
}

// 256 blocks x 512 threads. Block owns 32 rows (2 MFMA m-tiles shared by all 8
// waves); each wave owns a disjoint 1024-column range (64 iters x 16 cols).
// Single pass: S (neg exp-sum), E (all exp-sum), A (pos dot-sum) per row.
__global__ __launch_bounds__(512) void loss_kernel(const unsigned short* __restrict__ F16,
        const float* __restrict__ M, const int* __restrict__ labels,
        const int* __restrict__ cnt1, float* __restrict__ out) {
    __shared__ float sS[32], sE[32], sA[32];
    const int tid  = threadIdx.x;
    const int wave = tid >> 6, lane = tid & 63;
    const int quad = lane >> 4, l16 = lane & 15;
    const int rb   = blockIdx.x * 32;

    if (tid < 32) { sS[tid] = 0.f; sE[tid] = 0.f; sA[tid] = 0.f; }

    // A fragments: A[m = l16][k = quad*8 + j]  (verified m120 layout), 4 k-blocks
    bf16x8 a[2][4];
    #pragma unroll
    for (int m = 0; m < 2; m++)
        #pragma unroll
        for (int kb = 0; kb < 4; kb++)
            a[m][kb] = *reinterpret_cast<const bf16x8*>(
                F16 + (rb + m * 16 + l16) * DD + kb * 32 + quad * 8);

    // per-lane row invariants: D-frag row = quad*4 + r (+16 for m=1)
    float m2row[2][4]; int labr[2][4];
    #pragma unroll
    for (int m = 0; m < 2; m++)
        #pragma unroll
        for (int r = 0; r < 4; r++) {
            int row = rb + m * 16 + quad * 4 + r;
            m2row[m][r] = M[row] * LOG2E;
            labr[m][r]  = labels[row];
        }

    float accS[2][4] = {}, accE[2][4] = {}, accA[2][4] = {};

    const int c0 = wave * 1024;
    const unsigned short* Fb = F16 + (c0 + l16) * DD + quad * 8;

    // software-pipelined B fragments (B[k][n] = F[col][k] -> same pattern as A)
    bf16x8 bc[4]; int labc;
    #pragma unroll
    for (int kb = 0; kb < 4; kb++)
        bc[kb] = *reinterpret_cast<const bf16x8*>(Fb + kb * 32);
    labc = labels[c0 + l16];

    __syncthreads();   // covers sS/sE/sA init

    for (int it = 0; it < 64; ++it) {
        const int nxt = (it + 1) & 63;   // wrap: last prefetch is harmless
        bf16x8 bn[4];
        const unsigned short* Fn = Fb + nxt * 16 * DD;
        #pragma unroll
        for (int kb = 0; kb < 4; kb++)
            bn[kb] = *reinterpret_cast<const bf16x8*>(Fn + kb * 32);
        const int labn = labels[c0 + nxt * 16 + l16];

        f32x4 d0 = {0.f, 0.f, 0.f, 0.f}, d1 = {0.f, 0.f, 0.f, 0.f};
        #pragma unroll
        for (int kb = 0; kb < 4; kb++) {
            d0 = __builtin_amdgcn_mfma_f32_16x16x32_bf16(a[0][kb], bc[kb], d0, 0, 0, 0);
            d1 = __builtin_amdgcn_mfma_f32_16x16x32_bf16(a[1][kb], bc[kb], d1, 0, 0, 0);
        }

        #pragma unroll
        for (int m = 0; m < 2; m++) {
            #pragma unroll
            for (int r = 0; r < 4; r++) {
                const float v = (m == 0) ? d0[r] : d1[r];
                const float t = fmaf(v, K2f, -m2row[m][r]);   // l' * log2e
                const float e = exp2f(t);                     // exp(l')
                const bool eq = (labc == labr[m][r]);
                accE[m][r] += e;
                accS[m][r] += eq ? 0.f : e;
                accA[m][r] += eq ? v : 0.f;
            }
        }
        #pragma unroll
        for (int kb = 0; kb < 4; kb++) bc[kb] = bn[kb];
        labc = labn;
    }

    // reduce across the 16 lanes sharing a row (same quad), then across waves via LDS
    #pragma unroll
    for (int m = 0; m < 2; m++) {
        #pragma unroll
        for (int r = 0; r < 4; r++) {
            float s = accS[m][r], e = accE[m][r], aa = accA[m][r];
            #pragma unroll
            for (int off = 1; off < 16; off <<= 1) {
                s  += __shfl_xor(s,  off);
                e  += __shfl_xor(e,  off);
                aa += __shfl_xor(aa, off);
            }
            if (l16 == 0) {
                const int rl = m * 16 + quad * 4 + r;
                atomicAdd(&sS[rl], s);
                atomicAdd(&sE[rl], e);
                atomicAdd(&sA[rl], aa);
            }
        }
    }
    __syncthreads();

    if (wave == 0) {
        float li = 0.f;
        if (lane < 32) {
            const int row = rb + lane;
            const float Si   = sS[lane];
            const float Epos = sE[lane] - Si;      // pos exp-sum (incl diag)
            const float Ai   = sA[lane];           // pos dot-sum (incl diag)
            const float mi   = M[row];
            const int   lr   = labels[row];
            const int   c1   = *cnt1;
            const float cntp1 = (float)(lr ? c1 : (NN - c1));  // class count incl self
            const float cnt   = cntp1 - 1.f;                   // reference pos count
            const float sum_l   = fmaf(10.f, Ai, -cntp1 * mi); // sum_pos l'
            const float sum_log = cntp1 * __logf(Si) + Epos / Si;
            const float mlp = (sum_l - sum_log) / cnt;
            li = -(10.f / 7.f) * mlp;              // T/baseT = 0.1/0.07
        }
        #pragma unroll
        for (int off = 1; off < 64; off <<= 1) li += __shfl_xor(li, off);
        if (lane == 0) atomicAdd(out, li * (1.0f / NN));
    }
}

extern "C" void kernel_launch(void* const* d_in, const int* in_sizes, int n_in,
                              void* d_out, int out_size, void* d_ws, size_t ws_size,
                              hipStream_t stream) {
    const float* F      = (const float*)d_in[0];
    const int*   labels = (const int*)d_in[1];
    float*       out    = (float*)d_out;
    char*        ws     = (char*)d_ws;
    unsigned short* F16 = (unsigned short*)ws;
    float*       M      = (float*)(ws + M_OFF);
    int*         cnt1   = (int*)(ws + CNT_OFF);

    hipMemsetAsync(out, 0, sizeof(float), stream);
    hipMemsetAsync(cnt1, 0, sizeof(int), stream);

    prep_kernel<<<NN, 64, 0, stream>>>(F, labels, F16, M, cnt1);
    loss_kernel<<<NN / 32, 512, 0, stream>>>(F16, M, labels, cnt1, out);
}

// Round 2
// 131.494 us; speedup vs baseline: 1.6714x; 1.6714x over previous
//
#include <hip/hip_runtime.h>
#include <hip/hip_bf16.h>

#define NN 8192
#define DD 128

typedef short bf16x8 __attribute__((ext_vector_type(8)));
typedef float f32x4 __attribute__((ext_vector_type(4)));

#define LOG2E 1.4426950408889634f
#define K2f   14.426950408889634f   /* 10 * log2(e) */

// ws layout: [0, 2 MB) bf16 features; then N floats m_i; then one int class-count
#define M_OFF   (NN * DD * 2)
#define CNT_OFF (M_OFF + NN * 4)

__device__ __forceinline__ unsigned short f2bf(float x) {
    unsigned u = __float_as_uint(x);
    u = (u + 0x7FFFu + ((u >> 16) & 1u)) >> 16;   // RNE to bf16
    return (unsigned short)u;
}

// 256 blocks x 256 threads; block converts 32 rows, computes m_i, and counts
// label-1s with ONE global atomic per block (R1: 8192 same-address atomics
// serialized at ~11.6 ns each = 95 us; this cuts it to 256).
__global__ __launch_bounds__(256) void prep_kernel(const float* __restrict__ F,
        const int* __restrict__ labels, unsigned short* __restrict__ F16,
        float* __restrict__ M, int* __restrict__ cnt1) {
    __shared__ int scnt;
    const int tid = threadIdx.x;
    if (tid == 0) scnt = 0;
    __syncthreads();
    const int wave = tid >> 6, lane = tid & 63;
    const int half = lane >> 5, l32 = lane & 31;   // half-wave per row
    const int rb = blockIdx.x * 32;
    int mycnt = 0;
    #pragma unroll
    for (int it = 0; it < 4; ++it) {
        const int row = rb + it * 8 + wave * 2 + half;
        const float4 f = *reinterpret_cast<const float4*>(F + row * DD + l32 * 4);
        ushort4 u;
        u.x = f2bf(f.x); u.y = f2bf(f.y); u.z = f2bf(f.z); u.w = f2bf(f.w);
        *reinterpret_cast<ushort4*>(F16 + row * DD + l32 * 4) = u;
        float ss = fmaf(f.x, f.x, fmaf(f.y, f.y, fmaf(f.z, f.z, f.w * f.w)));
        #pragma unroll
        for (int off = 1; off < 32; off <<= 1) ss += __shfl_xor(ss, off);
        if (l32 == 0) {
            M[row] = 10.0f * ss;
            mycnt += labels[row];
        }
    }
    if (l32 == 0 && mycnt) atomicAdd(&scnt, mycnt);
    __syncthreads();
    if (tid == 0) atomicAdd(cnt1, scnt);
}

// 256 blocks x 512 threads. Block owns 32 rows (2 MFMA m-tiles shared by all 8
// waves); each wave owns a disjoint 1024-column range (64 iters x 16 cols).
// Single pass: S (neg exp-sum), E (all exp-sum), A (pos dot-sum) per row.
__global__ __launch_bounds__(512) void loss_kernel(const unsigned short* __restrict__ F16,
        const float* __restrict__ M, const int* __restrict__ labels,
        const int* __restrict__ cnt1, float* __restrict__ out) {
    __shared__ float sS[32], sE[32], sA[32];
    const int tid  = threadIdx.x;
    const int wave = tid >> 6, lane = tid & 63;
    const int quad = lane >> 4, l16 = lane & 15;
    const int rb   = blockIdx.x * 32;

    if (tid < 32) { sS[tid] = 0.f; sE[tid] = 0.f; sA[tid] = 0.f; }

    // A fragments: A[m = l16][k = quad*8 + j]  (verified m120 layout), 4 k-blocks
    bf16x8 a[2][4];
    #pragma unroll
    for (int m = 0; m < 2; m++)
        #pragma unroll
        for (int kb = 0; kb < 4; kb++)
            a[m][kb] = *reinterpret_cast<const bf16x8*>(
                F16 + (rb + m * 16 + l16) * DD + kb * 32 + quad * 8);

    // per-lane row invariants: D-frag row = quad*4 + r (+16 for m=1)
    float m2row[2][4]; int labr[2][4];
    #pragma unroll
    for (int m = 0; m < 2; m++)
        #pragma unroll
        for (int r = 0; r < 4; r++) {
            int row = rb + m * 16 + quad * 4 + r;
            m2row[m][r] = M[row] * LOG2E;
            labr[m][r]  = labels[row];
        }

    float accS[2][4] = {}, accE[2][4] = {}, accA[2][4] = {};

    const int c0 = wave * 1024;
    const unsigned short* Fb = F16 + (c0 + l16) * DD + quad * 8;

    // software-pipelined B fragments (B[k][n] = F[col][k] -> same pattern as A)
    bf16x8 bc[4]; int labc;
    #pragma unroll
    for (int kb = 0; kb < 4; kb++)
        bc[kb] = *reinterpret_cast<const bf16x8*>(Fb + kb * 32);
    labc = labels[c0 + l16];

    __syncthreads();   // covers sS/sE/sA init

    for (int it = 0; it < 64; ++it) {
        const int nxt = (it + 1) & 63;   // wrap: last prefetch is harmless
        bf16x8 bn[4];
        const unsigned short* Fn = Fb + nxt * 16 * DD;
        #pragma unroll
        for (int kb = 0; kb < 4; kb++)
            bn[kb] = *reinterpret_cast<const bf16x8*>(Fn + kb * 32);
        const int labn = labels[c0 + nxt * 16 + l16];

        f32x4 d0 = {0.f, 0.f, 0.f, 0.f}, d1 = {0.f, 0.f, 0.f, 0.f};
        #pragma unroll
        for (int kb = 0; kb < 4; kb++) {
            d0 = __builtin_amdgcn_mfma_f32_16x16x32_bf16(a[0][kb], bc[kb], d0, 0, 0, 0);
            d1 = __builtin_amdgcn_mfma_f32_16x16x32_bf16(a[1][kb], bc[kb], d1, 0, 0, 0);
        }

        #pragma unroll
        for (int m = 0; m < 2; m++) {
            #pragma unroll
            for (int r = 0; r < 4; r++) {
                const float v = (m == 0) ? d0[r] : d1[r];
                const float t = fmaf(v, K2f, -m2row[m][r]);   // l' * log2e
                const float e = exp2f(t);                     // exp(l')
                const bool eq = (labc == labr[m][r]);
                accE[m][r] += e;
                accS[m][r] += eq ? 0.f : e;
                accA[m][r] += eq ? v : 0.f;
            }
        }
        #pragma unroll
        for (int kb = 0; kb < 4; kb++) bc[kb] = bn[kb];
        labc = labn;
    }

    // reduce across the 16 lanes sharing a row (same quad), then across waves via LDS
    #pragma unroll
    for (int m = 0; m < 2; m++) {
        #pragma unroll
        for (int r = 0; r < 4; r++) {
            float s = accS[m][r], e = accE[m][r], aa = accA[m][r];
            #pragma unroll
            for (int off = 1; off < 16; off <<= 1) {
                s  += __shfl_xor(s,  off);
                e  += __shfl_xor(e,  off);
                aa += __shfl_xor(aa, off);
            }
            if (l16 == 0) {
                const int rl = m * 16 + quad * 4 + r;
                atomicAdd(&sS[rl], s);
                atomicAdd(&sE[rl], e);
                atomicAdd(&sA[rl], aa);
            }
        }
    }
    __syncthreads();

    if (wave == 0) {
        float li = 0.f;
        if (lane < 32) {
            const int row = rb + lane;
            const float Si   = sS[lane];
            const float Epos = sE[lane] - Si;      // pos exp-sum (incl diag)
            const float Ai   = sA[lane];           // pos dot-sum (incl diag)
            const float mi   = M[row];
            const int   lr   = labels[row];
            const int   c1   = *cnt1;
            const float cntp1 = (float)(lr ? c1 : (NN - c1));  // class count incl self
            const float cnt   = cntp1 - 1.f;                   // reference pos count
            const float sum_l   = fmaf(10.f, Ai, -cntp1 * mi); // sum_pos l'
            const float sum_log = cntp1 * __logf(Si) + Epos / Si;
            const float mlp = (sum_l - sum_log) / cnt;
            li = -(10.f / 7.f) * mlp;              // T/baseT = 0.1/0.07
        }
        #pragma unroll
        for (int off = 1; off < 64; off <<= 1) li += __shfl_xor(li, off);
        if (lane == 0) atomicAdd(out, li * (1.0f / NN));
    }
}

extern "C" void kernel_launch(void* const* d_in, const int* in_sizes, int n_in,
                              void* d_out, int out_size, void* d_ws, size_t ws_size,
                              hipStream_t stream) {
    const float* F      = (const float*)d_in[0];
    const int*   labels = (const int*)d_in[1];
    float*       out    = (float*)d_out;
    char*        ws     = (char*)d_ws;
    unsigned short* F16 = (unsigned short*)ws;
    float*       M      = (float*)(ws + M_OFF);
    int*         cnt1   = (int*)(ws + CNT_OFF);

    hipMemsetAsync(out, 0, sizeof(float), stream);
    hipMemsetAsync(cnt1, 0, sizeof(int), stream);

    prep_kernel<<<NN / 32, 256, 0, stream>>>(F, labels, F16, M, cnt1);
    loss_kernel<<<NN / 32, 512, 0, stream>>>(F16, M, labels, cnt1, out);
}